// Round 2
// baseline (431.942 us; speedup 1.0000x reference)
//
#include <hip/hip_runtime.h>

typedef unsigned short u16;
typedef unsigned int   u32;

#define NQd 10000
#define NSd 500
#define Bd  32
#define Sd  200
#define Td  199   // S-1
#define Dd  128

__device__ __forceinline__ float sigf(float x) { return 1.f / (1.f + __expf(-x)); }
__device__ __forceinline__ float bf2f(u16 u) { return __uint_as_float(((u32)u) << 16); }
__device__ __forceinline__ u16 f2bf(float f) {            // round-to-nearest-even
  u32 b = __float_as_uint(f);
  b += 0x7FFFu + ((b >> 16) & 1u);
  return (u16)(b >> 16);
}

// ---------------------------------------------------------------------------
// Table stage: out[row][0..127] = act( in[row] @ W + bias )
// in[row][d] = A[arow][d] + (1/K) * mean_l Bt[nbr[arow*K+l]][d], arow = rowmap?rowmap[row]:row
// W element (d,e) at W[d*w_stride + w_off + e] (f32). bias: per-col f32 (cbias)
// or per-row f32 (rbias[rbias_idx[row]*512 + rb_off + e]).
// ACT: 0=tanh 1=relu 2=none. K is compile-time (0/4/10).
// Block: 128 threads, tile 32 rows x 128 cols, thread tile 4x8.
// K-dim split in two 64-wide panels so f32 W tile fits LDS (32KB + 8KB).
// ---------------------------------------------------------------------------
template <int K, int ACT>
__global__ __launch_bounds__(128) void stage_gemm(
    const float* __restrict__ A,
    const float* __restrict__ Bt,
    const int* __restrict__ nbr,
    const int* __restrict__ rowmap,
    const float* __restrict__ W, int w_stride, int w_off,
    const float* __restrict__ cbias,
    const float* __restrict__ rbias, const int* __restrict__ rbias_idx, int rb_off,
    float* __restrict__ out, int rows)
{
  __shared__ __align__(16) float Wl[64 * 128];   // 32 KB
  __shared__ __align__(16) float InT[64 * 32];   // 8 KB
  const int tid = threadIdx.x;
  const int tile0 = blockIdx.x * 32;

  const int r = tid & 31, sub = tid >> 5;          // staging roles
  int row = tile0 + r; if (row > rows - 1) row = rows - 1;
  const int arow = rowmap ? rowmap[row] : row;
  int ids[K > 0 ? K : 1];
#pragma unroll
  for (int l = 0; l < K; ++l) ids[l] = nbr[(long)arow * K + l];
  const float inv = (K > 0) ? (1.f / (float)K) : 0.f;

  const int rt = tid & 7;     // compute: rows rt*4..+3
  const int et = tid >> 3;    // compute: cols et*8..+7
  float acc[4][8];
#pragma unroll
  for (int i = 0; i < 4; ++i)
#pragma unroll
    for (int j = 0; j < 8; ++j) acc[i][j] = 0.f;

#pragma unroll
  for (int kp = 0; kp < 2; ++kp) {
    const int db = kp << 6;
    // stage W panel [db..db+63][0..127]
    for (int idx = tid; idx < 2048; idx += 128) {
      int lin = idx << 2;
      int d = lin >> 7, e = lin & 127;
      *reinterpret_cast<float4*>(&Wl[lin]) =
          *reinterpret_cast<const float4*>(&W[(long)(db + d) * w_stride + w_off + e]);
    }
    // stage input panel transposed [d][r]
#pragma unroll
    for (int c = 0; c < 16; c += 4) {
      int d = (sub << 4) + c;
      float4 v = *reinterpret_cast<const float4*>(&A[(long)arow * Dd + db + d]);
      if (K > 0) {
        float sx = 0, sy = 0, sz = 0, sw = 0;
#pragma unroll
        for (int l = 0; l < K; ++l) {
          float4 s = *reinterpret_cast<const float4*>(&Bt[(long)ids[l] * Dd + db + d]);
          sx += s.x; sy += s.y; sz += s.z; sw += s.w;
        }
        v.x += sx * inv; v.y += sy * inv; v.z += sz * inv; v.w += sw * inv;
      }
      InT[(d + 0) * 32 + r] = v.x;
      InT[(d + 1) * 32 + r] = v.y;
      InT[(d + 2) * 32 + r] = v.z;
      InT[(d + 3) * 32 + r] = v.w;
    }
    __syncthreads();
#pragma unroll 8
    for (int d = 0; d < 64; ++d) {
      float4 a  = *reinterpret_cast<const float4*>(&InT[d * 32 + rt * 4]);
      float4 w0 = *reinterpret_cast<const float4*>(&Wl[d * 128 + et * 8]);
      float4 w1 = *reinterpret_cast<const float4*>(&Wl[d * 128 + et * 8 + 4]);
      float av[4] = {a.x, a.y, a.z, a.w};
      float wv[8] = {w0.x, w0.y, w0.z, w0.w, w1.x, w1.y, w1.z, w1.w};
#pragma unroll
      for (int i = 0; i < 4; ++i)
#pragma unroll
        for (int j = 0; j < 8; ++j) acc[i][j] = fmaf(av[i], wv[j], acc[i][j]);
    }
    __syncthreads();
  }

  // epilogue
  float bj[8];
  if (rbias == nullptr) {
    *reinterpret_cast<float4*>(&bj[0]) = *reinterpret_cast<const float4*>(&cbias[et * 8]);
    *reinterpret_cast<float4*>(&bj[4]) = *reinterpret_cast<const float4*>(&cbias[et * 8 + 4]);
  }
#pragma unroll
  for (int i = 0; i < 4; ++i) {
    int orow = tile0 + rt * 4 + i;
    if (orow >= rows) continue;
    if (rbias != nullptr) {
      const float* rb = rbias + (long)rbias_idx[orow] * 512 + rb_off + et * 8;
#pragma unroll
      for (int j = 0; j < 8; ++j) bj[j] = rb[j];
    }
    float o[8];
#pragma unroll
    for (int j = 0; j < 8; ++j) {
      float v = acc[i][j] + bj[j];
      if (ACT == 0) v = tanhf(v);
      else if (ACT == 1) v = fmaxf(v, 0.f);
      o[j] = v;
    }
    *reinterpret_cast<float4*>(&out[(long)orow * Dd + et * 8])     = make_float4(o[0], o[1], o[2], o[3]);
    *reinterpret_cast<float4*>(&out[(long)orow * Dd + et * 8 + 4]) = make_float4(o[4], o[5], o[6], o[7]);
  }
}

// ---------------------------------------------------------------------------
// prep_small: qw[d]=sum_e q_W[d][e]*w_W[e]; kw[d]=sum_e k_W[d][e]*w_W[D+e];
// scal[0]=q_b.w_W[:D], scal[1]=k_b.w_W[D:];
// er_part[r][e]=b_ih[e]+b_hh[e]+emb_r[r]@W_ih[128:256,:][*,e]
// ---------------------------------------------------------------------------
__global__ __launch_bounds__(512) void prep_small(
    const float* __restrict__ q_W, const float* __restrict__ q_b,
    const float* __restrict__ k_W, const float* __restrict__ k_b,
    const float* __restrict__ w_W,
    const float* __restrict__ W_ih, const float* __restrict__ b_ih, const float* __restrict__ b_hh,
    const float* __restrict__ emb_r,
    float* __restrict__ qw, float* __restrict__ kw, float* __restrict__ scal,
    float* __restrict__ er_part)
{
  int tid = threadIdx.x;
  if (tid < 128) {
    float s = 0;
    for (int e = 0; e < 128; ++e) s += q_W[tid * 128 + e] * w_W[e];
    qw[tid] = s;
  } else if (tid < 256) {
    int d = tid - 128; float s = 0;
    for (int e = 0; e < 128; ++e) s += k_W[d * 128 + e] * w_W[128 + e];
    kw[d] = s;
  } else if (tid == 256) {
    float s = 0;
    for (int e = 0; e < 128; ++e) s += q_b[e] * w_W[e];
    scal[0] = s;
  } else if (tid == 257) {
    float s = 0;
    for (int e = 0; e < 128; ++e) s += k_b[e] * w_W[128 + e];
    scal[1] = s;
  }
  for (int idx = tid; idx < 1024; idx += 512) {
    int rr = idx >> 9, e = idx & 511;
    float s = b_ih[e] + b_hh[e];
    for (int d = 0; d < 128; ++d) s += emb_r[rr * Dd + d] * W_ih[(128 + d) * 512 + e];
    er_part[rr * 512 + e] = s;
  }
}

__global__ void prep_maps(const int* __restrict__ question, const int* __restrict__ response,
                          int* __restrict__ qid_map, int* __restrict__ resp_map)
{
  int idx = blockIdx.x * 256 + threadIdx.x;
  if (idx >= Bd * Td) return;
  int b = idx / Td, s = idx - b * Td;
  qid_map[idx]  = question[b * Sd + s];
  resp_map[idx] = response[b * Sd + s];
}

// pm[q][m] = softmax_m( dot(qs_vec[q,m], kw) + scal[1] )
__global__ __launch_bounds__(256) void pm_kernel(
    const float* __restrict__ emb_q, const float* __restrict__ emb_s,
    const int* __restrict__ qs_skills,
    const float* __restrict__ kw, const float* __restrict__ scal,
    float* __restrict__ pm)
{
  int qid = blockIdx.x * 4 + (threadIdx.x >> 6);
  int lane = threadIdx.x & 63;
  if (qid >= NQd) return;
  float a[5];
  for (int m = 0; m < 5; ++m) {
    const float* src = (m == 0) ? emb_q + (long)qid * Dd
                                : emb_s + (long)qs_skills[qid * 4 + (m - 1)] * Dd;
    float p = src[lane] * kw[lane] + src[lane + 64] * kw[lane + 64];
    for (int off = 32; off > 0; off >>= 1) p += __shfl_xor(p, off);
    a[m] = p + scal[1];
  }
  float mx = a[0];
  for (int m = 1; m < 5; ++m) mx = fmaxf(mx, a[m]);
  float z = 0, ex[5];
  for (int m = 0; m < 5; ++m) { ex[m] = __expf(a[m] - mx); z += ex[m]; }
  if (lane < 5) pm[(long)qid * 5 + lane] = ex[lane] / z;
}

// pointwise LSTM cell (no recurrence; f-gate dead) + fused a_state = h.qw + scal[0]
__global__ __launch_bounds__(128) void lstm_point(
    const float* __restrict__ ig, const float* __restrict__ gg, const float* __restrict__ og,
    const float* __restrict__ qw, const float* __restrict__ scal,
    float* __restrict__ states, float* __restrict__ a_state)
{
  __shared__ float red[128];
  int rr = blockIdx.x, e = threadIdx.x;
  long idx = (long)rr * Dd + e;
  float c = sigf(ig[idx]) * tanhf(gg[idx]);
  float h = sigf(og[idx]) * tanhf(c);
  states[idx] = h;
  red[e] = h * qw[e];
  __syncthreads();
  for (int s = 64; s > 0; s >>= 1) { if (e < s) red[e] += red[e + s]; __syncthreads(); }
  if (e == 0) a_state[rr] = red[0] + scal[0];
}

// G[b][col][n] = sigmoid( states[b,n] . qs_vec[b, col] ), col = t*5+m  (bf16 storage)
__global__ __launch_bounds__(128) void g_gemm(
    const float* __restrict__ states,
    const int* __restrict__ question,
    const int* __restrict__ qs_skills,
    const float* __restrict__ emb_q, const float* __restrict__ emb_s,
    u16* __restrict__ G)
{
  const int n0 = blockIdx.x * 32;
  const int c0 = blockIdx.y * 128;
  const int b  = blockIdx.z;
  int c_hi = c0 + 127; if (c_hi > 994) c_hi = 994;
  if (n0 > c_hi / 5) return;  // whole tile has n > t : never read

  __shared__ __align__(16) float QS[64 * 128];   // 32 KB [d][j]
  __shared__ __align__(16) float InT[64 * 32];   // 8 KB  [d][r]
  const int tid = threadIdx.x;

  // per-thread column source pointer
  const int j = tid;
  const int col = c0 + j;
  const int valid = (col < 995);
  int t = valid ? (col / 5) : 0;
  int m = valid ? (col - t * 5) : 0;
  int qn = question[b * Sd + t + 1];
  const float* src = (m == 0) ? emb_q + (long)qn * Dd
                              : emb_s + (long)qs_skills[qn * 4 + (m - 1)] * Dd;

  const int r = tid & 31, sub = tid >> 5;
  int n = n0 + r; if (n > 198) n = 198;
  const float* srow = states + ((long)b * Td + n) * Dd;

  const int rt = tid & 7, et = tid >> 3;
  float acc[4][8];
#pragma unroll
  for (int i = 0; i < 4; ++i)
#pragma unroll
    for (int jj = 0; jj < 8; ++jj) acc[i][jj] = 0.f;

#pragma unroll
  for (int kp = 0; kp < 2; ++kp) {
    const int db = kp << 6;
#pragma unroll
    for (int c = 0; c < 64; c += 4) {
      float4 v = valid ? *reinterpret_cast<const float4*>(&src[db + c])
                       : make_float4(0.f, 0.f, 0.f, 0.f);
      QS[(c + 0) * 128 + j] = v.x;
      QS[(c + 1) * 128 + j] = v.y;
      QS[(c + 2) * 128 + j] = v.z;
      QS[(c + 3) * 128 + j] = v.w;
    }
#pragma unroll
    for (int c = 0; c < 16; c += 4) {
      int d = (sub << 4) + c;
      float4 v = *reinterpret_cast<const float4*>(&srow[db + d]);
      InT[(d + 0) * 32 + r] = v.x;
      InT[(d + 1) * 32 + r] = v.y;
      InT[(d + 2) * 32 + r] = v.z;
      InT[(d + 3) * 32 + r] = v.w;
    }
    __syncthreads();
#pragma unroll 8
    for (int d = 0; d < 64; ++d) {
      float4 a  = *reinterpret_cast<const float4*>(&InT[d * 32 + rt * 4]);
      float4 w0 = *reinterpret_cast<const float4*>(&QS[d * 128 + et * 8]);
      float4 w1 = *reinterpret_cast<const float4*>(&QS[d * 128 + et * 8 + 4]);
      float av[4] = {a.x, a.y, a.z, a.w};
      float wv[8] = {w0.x, w0.y, w0.z, w0.w, w1.x, w1.y, w1.z, w1.w};
#pragma unroll
      for (int i = 0; i < 4; ++i)
#pragma unroll
        for (int jj = 0; jj < 8; ++jj) acc[i][jj] = fmaf(av[i], wv[jj], acc[i][jj]);
    }
    __syncthreads();
  }

  int nstart = n0 + rt * 4;
  if (nstart > 196) return;  // n rows 196..199 written by nstart==196; >=200 OOB
#pragma unroll
  for (int jj = 0; jj < 8; ++jj) {
    int ocol = c0 + et * 8 + jj;
    if (ocol >= 995) continue;
    u32 p0 = (u32)f2bf(sigf(acc[0][jj])) | ((u32)f2bf(sigf(acc[1][jj])) << 16);
    u32 p1 = (u32)f2bf(sigf(acc[2][jj])) | ((u32)f2bf(sigf(acc[3][jj])) << 16);
    long idx = ((long)b * 1000 + ocol) * 200 + nstart;   // idx % 4 == 0 -> 8B aligned
    *reinterpret_cast<uint2*>(&G[idx]) = make_uint2(p0, p1);
  }
}

// pred[b,t] = sum_{n<=t} pn(n) * sum_m pm(m) * G[b][t*5+m][n] ; out col 0 = 0
__global__ __launch_bounds__(256) void pred_kernel(
    const u16* __restrict__ G, const float* __restrict__ a_state,
    const float* __restrict__ pm, const int* __restrict__ question,
    float* __restrict__ out)
{
  __shared__ float red[256];
  int bt = blockIdx.x;
  int b = bt / Td, t = bt - b * Td;
  int tid = threadIdx.x;

  float v = (tid <= t) ? a_state[b * Td + tid] : -1e30f;
  red[tid] = v; __syncthreads();
  for (int s = 128; s > 0; s >>= 1) { if (tid < s) red[tid] = fmaxf(red[tid], red[tid + s]); __syncthreads(); }
  float amax = red[0]; __syncthreads();

  float ev = (tid <= t) ? __expf(v - amax) : 0.f;
  red[tid] = ev; __syncthreads();
  for (int s = 128; s > 0; s >>= 1) { if (tid < s) red[tid] += red[tid + s]; __syncthreads(); }
  float Z = red[0]; __syncthreads();

  int qn = question[b * Sd + t + 1];
  float p0 = pm[(long)qn * 5 + 0], p1 = pm[(long)qn * 5 + 1], p2 = pm[(long)qn * 5 + 2];
  float p3 = pm[(long)qn * 5 + 3], p4 = pm[(long)qn * 5 + 4];

  float acc = 0.f;
  if (tid <= t) {
    long base = ((long)b * 1000 + (long)t * 5) * 200 + tid;
    float s = p0 * bf2f(G[base])       + p1 * bf2f(G[base + 200]) +
              p2 * bf2f(G[base + 400]) + p3 * bf2f(G[base + 600]) +
              p4 * bf2f(G[base + 800]);
    acc = ev * s;
  }
  red[tid] = acc; __syncthreads();
  for (int s = 128; s > 0; s >>= 1) { if (tid < s) red[tid] += red[tid + s]; __syncthreads(); }
  if (tid == 0) {
    out[b * Sd + t + 1] = red[0] / Z;
    if (t == 0) out[b * Sd] = 0.f;
  }
}

// ---------------------------------------------------------------------------
extern "C" void kernel_launch(void* const* d_in, const int* in_sizes, int n_in,
                              void* d_out, int out_size, void* d_ws, size_t ws_size,
                              hipStream_t stream)
{
  const int*   question = (const int*)d_in[0];
  const int*   response = (const int*)d_in[1];
  const int*   q_nb     = (const int*)d_in[3];
  const int*   s_nb     = (const int*)d_in[4];
  const int*   qs_sk    = (const int*)d_in[5];
  const float* emb_q    = (const float*)d_in[6];
  const float* emb_s    = (const float*)d_in[7];
  const float* emb_r    = (const float*)d_in[8];
  const float* W_ih     = (const float*)d_in[9];
  const float* b_ih     = (const float*)d_in[10];
  const float* b_hh     = (const float*)d_in[11];
  const float* ft_W     = (const float*)d_in[12];
  const float* ft_b     = (const float*)d_in[13];
  const float* agg_W    = (const float*)d_in[14];
  const float* agg_b    = (const float*)d_in[15];
  const float* last_W   = (const float*)d_in[16];
  const float* last_b   = (const float*)d_in[17];
  const float* q_W      = (const float*)d_in[18];
  const float* q_b      = (const float*)d_in[19];
  const float* k_W      = (const float*)d_in[20];
  const float* k_b      = (const float*)d_in[21];
  const float* w_W      = (const float*)d_in[22];

  float* ws = (float*)d_ws;
  const long NT = (long)NQd * Dd;       // 1,280,000
  const long ST = (long)NSd * Dd;       //    64,000
  const long RT = (long)Bd * Td * Dd;   //   815,104
  // Buffer-reuse chain: A=f2->h0->ig, B=f0->agg->gg, C=g0->qt, OG=og.
  // G (bf16, 6.4M u16 = 3.2M float-equiv) overlays A..C (all dead by g_gemm).
  float* A  = ws;            // NT
  float* Bu = A + NT;        // NT
  float* C  = Bu + NT;       // NT
  float* s1 = C + NT;        // ST
  float* s2 = s1 + ST;       // ST
  float* OG = s2 + ST;       // RT
  float* states  = OG + RT;  // RT
  float* a_state = states + RT;      // 6400
  float* qw      = a_state + 6400;   // 128
  float* kw      = qw + 128;         // 128
  float* scal    = kw + 128;         // 16
  float* er_part = scal + 16;        // 1024
  float* pm      = er_part + 1024;   // 50000
  int* qid_map   = (int*)(pm + (long)NQd * 5);
  int* resp_map  = qid_map + Bd * Td;
  u16* G         = (u16*)ws;         // 6,400,000 u16 within A..C region

  prep_small<<<1, 512, 0, stream>>>(q_W, q_b, k_W, k_b, w_W, W_ih, b_ih, b_hh, emb_r,
                                    qw, kw, scal, er_part);
  prep_maps<<<(Bd * Td + 255) / 256, 256, 0, stream>>>(question, response, qid_map, resp_map);
  pm_kernel<<<NQd / 4, 256, 0, stream>>>(emb_q, emb_s, qs_sk, kw, scal, pm);

  // hop 0
  stage_gemm<4, 0><<<313, 128, 0, stream>>>(emb_q, emb_s, q_nb, nullptr,
      agg_W + 2 * 16384, 128, 0, agg_b + 2 * 128, nullptr, nullptr, 0, A, NQd);   // f2
  stage_gemm<10, 0><<<16, 128, 0, stream>>>(emb_s, emb_q, s_nb, nullptr,
      agg_W + 16384, 128, 0, agg_b + 128, nullptr, nullptr, 0, s1, NSd);          // f1
  stage_gemm<4, 0><<<313, 128, 0, stream>>>(emb_q, emb_s, q_nb, nullptr,
      agg_W, 128, 0, agg_b, nullptr, nullptr, 0, Bu, NQd);                        // f0
  // hop 1
  stage_gemm<10, 0><<<16, 128, 0, stream>>>(s1, A, s_nb, nullptr,
      agg_W + 16384, 128, 0, agg_b + 128, nullptr, nullptr, 0, s2, NSd);          // g1
  stage_gemm<4, 0><<<313, 128, 0, stream>>>(Bu, s1, q_nb, nullptr,
      agg_W, 128, 0, agg_b, nullptr, nullptr, 0, C, NQd);                         // g0
  // hop 2
  stage_gemm<4, 0><<<313, 128, 0, stream>>>(C, s2, q_nb, nullptr,
      agg_W, 128, 0, agg_b, nullptr, nullptr, 0, A, NQd);                         // h0
  // agg = tanh(h0 @ last_W + last_b)
  stage_gemm<0, 0><<<313, 128, 0, stream>>>(A, nullptr, nullptr, nullptr,
      last_W, 128, 0, last_b, nullptr, nullptr, 0, Bu, NQd);                      // agg
  // qt = relu(agg @ ft_W + ft_b)
  stage_gemm<0, 1><<<313, 128, 0, stream>>>(Bu, nullptr, nullptr, nullptr,
      ft_W, 128, 0, ft_b, nullptr, nullptr, 0, C, NQd);                           // qt
  // gates (i, g, o): rows=(b,s) s<199; per-row bias er_part[resp]
  stage_gemm<0, 2><<<199, 128, 0, stream>>>(C, nullptr, nullptr, qid_map,
      W_ih, 512, 0, nullptr, er_part, resp_map, 0, A, Bd * Td);                   // ig
  stage_gemm<0, 2><<<199, 128, 0, stream>>>(C, nullptr, nullptr, qid_map,
      W_ih, 512, 256, nullptr, er_part, resp_map, 256, Bu, Bd * Td);              // gg
  stage_gemm<0, 2><<<199, 128, 0, stream>>>(C, nullptr, nullptr, qid_map,
      W_ih, 512, 384, nullptr, er_part, resp_map, 384, OG, Bd * Td);              // og

  lstm_point<<<Bd * Td, 128, 0, stream>>>(A, Bu, OG, qw, scal, states, a_state);

  g_gemm<<<dim3(7, 8, Bd), 128, 0, stream>>>(states, question, qs_sk, emb_q, emb_s, G);

  pred_kernel<<<Bd * Td, 256, 0, stream>>>(G, a_state, pm, question, (float*)d_out);
}

// Round 3
// 265.253 us; speedup vs baseline: 1.6284x; 1.6284x over previous
//
#include <hip/hip_runtime.h>

typedef unsigned short u16;
typedef unsigned int   u32;

#define NQd 10000
#define NSd 500
#define Bd  32
#define Sd  200
#define Td  199   // S-1
#define Dd  128

typedef __attribute__((ext_vector_type(8))) short bf16x8;
typedef __attribute__((ext_vector_type(4))) float f32x4;

__device__ __forceinline__ float sigf(float x) { return 1.f / (1.f + __expf(-x)); }
__device__ __forceinline__ float bf2f(u16 u) { return __uint_as_float(((u32)u) << 16); }
__device__ __forceinline__ u16 f2bf(float f) {            // round-to-nearest-even
  u32 b = __float_as_uint(f);
  b += 0x7FFFu + ((b >> 16) & 1u);
  return (u16)(b >> 16);
}
__device__ __forceinline__ void unp2(u32 u, float &a, float &b) {
  a = __uint_as_float(u << 16);
  b = __uint_as_float(u & 0xffff0000u);
}
__device__ __forceinline__ void unpack16(uint4 a0, uint4 a1, float* f) {
  unp2(a0.x, f[0], f[1]);  unp2(a0.y, f[2], f[3]);
  unp2(a0.z, f[4], f[5]);  unp2(a0.w, f[6], f[7]);
  unp2(a1.x, f[8], f[9]);  unp2(a1.y, f[10], f[11]);
  unp2(a1.z, f[12], f[13]); unp2(a1.w, f[14], f[15]);
}

// ---------------------------------------------------------------------------
// prep_w: build bf16 copies of emb tables (row-major [id][k]) and bf16
// TRANSPOSED weights Wt[col][k] so MFMA B-fragments are contiguous in LDS.
// wts = aggt0 | aggt1 | aggt2 | lastt | ftt (5 x 16384). wiht = 512x128.
// ---------------------------------------------------------------------------
__global__ __launch_bounds__(256) void prep_w(
    const float* __restrict__ emb_q, const float* __restrict__ emb_s,
    const float* __restrict__ agg_W, const float* __restrict__ last_W,
    const float* __restrict__ ft_W,  const float* __restrict__ W_ih,
    u16* __restrict__ embq_bf, u16* __restrict__ embs_bf,
    u16* __restrict__ wts, u16* __restrict__ wiht)
{
  const int total = 1280000 + 64000 + 5 * 16384 + 65536;  // 1,491,456
  for (int i = blockIdx.x * 256 + threadIdx.x; i < total; i += gridDim.x * 256) {
    if (i < 1280000) {
      embq_bf[i] = f2bf(emb_q[i]);
    } else if (i < 1344000) {
      int e = i - 1280000;
      embs_bf[e] = f2bf(emb_s[e]);
    } else if (i < 1425920) {
      int e = i - 1344000;
      int seg = e >> 14, r = e & 16383;
      int col = r >> 7, k = r & 127;
      const float* src = (seg < 3) ? (agg_W + seg * 16384) : (seg == 3 ? last_W : ft_W);
      wts[e] = f2bf(src[k * 128 + col]);
    } else {
      int e = i - 1425920;
      int col = e >> 7, k = e & 127;
      wiht[e] = f2bf(W_ih[k * 512 + col]);
    }
  }
}

// ---------------------------------------------------------------------------
// MFMA table stage: out[row][0..127] = act( in[row] @ W + bias ), bf16 I/O.
// in[row] = Atab[arow] + mean_l Btab[nbr[arow*K+l]]; arow = rowmap?rowmap[row]:row.
// Wt is bf16 [col][128] (pre-transposed). bias: per-col f32 cbias OR per-row
// f32 rbias[rbias_idx[row]*512 + rb_off + col]. act: 0=tanh 1=relu 2=none.
// gate3: blockIdx.y in {0,1,2} selects gate (wt_col0/rb_off = {0,256,384},
// out += y*rows*128). Block 256 thr = 4 waves; tile 32 rows x 128 cols.
// ---------------------------------------------------------------------------
__global__ __launch_bounds__(256) void stage_mfma(
    const u16* __restrict__ Atab, const u16* __restrict__ Btab,
    const int* __restrict__ nbr, int K,
    const int* __restrict__ rowmap,
    const u16* __restrict__ Wt, int wt_col0,
    const float* __restrict__ cbias,
    const float* __restrict__ rbias, const int* __restrict__ rbias_idx, int rb_off,
    u16* __restrict__ out, int rows, int act, int gate3)
{
  __shared__ __align__(16) u16 Wl[128 * 136];  // [col][k], pad +8 -> 2-way banks (free)
  __shared__ __align__(16) u16 Al[32 * 136];   // [row][k]
  const int tid = threadIdx.x;
  const int tile0 = blockIdx.x * 32;
  if (gate3) {
    int y = blockIdx.y;
    wt_col0 = (y == 0) ? 0 : (y == 1 ? 256 : 384);
    rb_off = wt_col0;
    out += (long)y * rows * 128;
  }
  // stage Wt tile: 128 cols x 256 B, contiguous 16B chunks
  for (int i = tid; i < 2048; i += 256) {
    int col = i >> 4, seg = i & 15;
    *(uint4*)&Wl[col * 136 + seg * 8] =
        *(const uint4*)&Wt[((long)(wt_col0 + col)) * 128 + seg * 8];
  }
  // stage A tile (gather + neighbor mean in f32, repack bf16)
  {
    int r = tid & 31, k0 = (tid >> 5) * 16;
    int row = tile0 + r; if (row >= rows) row = rows - 1;
    int arow = rowmap ? rowmap[row] : row;
    const u16* ap = Atab + (long)arow * 128 + k0;
    float f[16];
    unpack16(*(const uint4*)ap, *(const uint4*)(ap + 8), f);
    if (K > 0) {
      float s[16];
#pragma unroll
      for (int q = 0; q < 16; ++q) s[q] = 0.f;
      for (int l = 0; l < K; ++l) {
        int id = nbr[(long)arow * K + l];
        const u16* np = Btab + (long)id * 128 + k0;
        float g[16];
        unpack16(*(const uint4*)np, *(const uint4*)(np + 8), g);
#pragma unroll
        for (int q = 0; q < 16; ++q) s[q] += g[q];
      }
      float inv = 1.f / (float)K;
#pragma unroll
      for (int q = 0; q < 16; ++q) f[q] += s[q] * inv;
    }
    u32 p[8];
#pragma unroll
    for (int q = 0; q < 8; ++q)
      p[q] = (u32)f2bf(f[2 * q]) | ((u32)f2bf(f[2 * q + 1]) << 16);
    *(uint4*)&Al[r * 136 + k0]     = make_uint4(p[0], p[1], p[2], p[3]);
    *(uint4*)&Al[r * 136 + k0 + 8] = make_uint4(p[4], p[5], p[6], p[7]);
  }
  __syncthreads();

  const int lane = tid & 63, wv = tid >> 6;
  const int l15 = lane & 15, quad = lane >> 4;
  const int cw = wv * 32;
  f32x4 acc[2][2];
#pragma unroll
  for (int a = 0; a < 2; ++a)
#pragma unroll
    for (int bb = 0; bb < 2; ++bb) acc[a][bb] = (f32x4){0.f, 0.f, 0.f, 0.f};

#pragma unroll
  for (int kc = 0; kc < 4; ++kc) {
    const int ko = kc * 32 + quad * 8;
    bf16x8 af[2], bfv[2];
    af[0]  = *(const bf16x8*)&Al[l15 * 136 + ko];
    af[1]  = *(const bf16x8*)&Al[(16 + l15) * 136 + ko];
    bfv[0] = *(const bf16x8*)&Wl[(cw + l15) * 136 + ko];
    bfv[1] = *(const bf16x8*)&Wl[(cw + 16 + l15) * 136 + ko];
#pragma unroll
    for (int mt = 0; mt < 2; ++mt)
#pragma unroll
      for (int nt = 0; nt < 2; ++nt)
        acc[mt][nt] = __builtin_amdgcn_mfma_f32_16x16x32_bf16(af[mt], bfv[nt], acc[mt][nt], 0, 0, 0);
  }

  // epilogue: D layout col=lane&15, row=quad*4+reg
#pragma unroll
  for (int nt = 0; nt < 2; ++nt) {
    int col = cw + nt * 16 + l15;
    float cb = (rbias == nullptr) ? cbias[col] : 0.f;
#pragma unroll
    for (int mt = 0; mt < 2; ++mt) {
      int rbase = tile0 + mt * 16 + quad * 4;
#pragma unroll
      for (int i = 0; i < 4; ++i) {
        int row = rbase + i;
        if (row >= rows) continue;
        float bias = (rbias != nullptr)
                   ? rbias[(long)rbias_idx[row] * 512 + rb_off + col] : cb;
        float v = acc[mt][nt][i] + bias;
        if (act == 0) v = tanhf(v);
        else if (act == 1) v = fmaxf(v, 0.f);
        out[(long)row * 128 + col] = f2bf(v);
      }
    }
  }
}

// ---------------------------------------------------------------------------
// prep_small (f32 originals): qw/kw/scal/er_part — unchanged from R2
// ---------------------------------------------------------------------------
__global__ __launch_bounds__(512) void prep_small(
    const float* __restrict__ q_W, const float* __restrict__ q_b,
    const float* __restrict__ k_W, const float* __restrict__ k_b,
    const float* __restrict__ w_W,
    const float* __restrict__ W_ih, const float* __restrict__ b_ih, const float* __restrict__ b_hh,
    const float* __restrict__ emb_r,
    float* __restrict__ qw, float* __restrict__ kw, float* __restrict__ scal,
    float* __restrict__ er_part)
{
  int tid = threadIdx.x;
  if (tid < 128) {
    float s = 0;
    for (int e = 0; e < 128; ++e) s += q_W[tid * 128 + e] * w_W[e];
    qw[tid] = s;
  } else if (tid < 256) {
    int d = tid - 128; float s = 0;
    for (int e = 0; e < 128; ++e) s += k_W[d * 128 + e] * w_W[128 + e];
    kw[d] = s;
  } else if (tid == 256) {
    float s = 0;
    for (int e = 0; e < 128; ++e) s += q_b[e] * w_W[e];
    scal[0] = s;
  } else if (tid == 257) {
    float s = 0;
    for (int e = 0; e < 128; ++e) s += k_b[e] * w_W[128 + e];
    scal[1] = s;
  }
  for (int idx = tid; idx < 1024; idx += 512) {
    int rr = idx >> 9, e = idx & 511;
    float s = b_ih[e] + b_hh[e];
    for (int d = 0; d < 128; ++d) s += emb_r[rr * Dd + d] * W_ih[(128 + d) * 512 + e];
    er_part[rr * 512 + e] = s;
  }
}

__global__ void prep_maps(const int* __restrict__ question, const int* __restrict__ response,
                          int* __restrict__ qid_map, int* __restrict__ resp_map)
{
  int idx = blockIdx.x * 256 + threadIdx.x;
  if (idx >= Bd * Td) return;
  int b = idx / Td, s = idx - b * Td;
  qid_map[idx]  = question[b * Sd + s];
  resp_map[idx] = response[b * Sd + s];
}

// pm[q][m] = softmax_m( dot(qs_vec[q,m], kw) + scal[1] )  (f32 emb reads)
__global__ __launch_bounds__(256) void pm_kernel(
    const float* __restrict__ emb_q, const float* __restrict__ emb_s,
    const int* __restrict__ qs_skills,
    const float* __restrict__ kw, const float* __restrict__ scal,
    float* __restrict__ pm)
{
  int qid = blockIdx.x * 4 + (threadIdx.x >> 6);
  int lane = threadIdx.x & 63;
  if (qid >= NQd) return;
  float a[5];
  for (int m = 0; m < 5; ++m) {
    const float* src = (m == 0) ? emb_q + (long)qid * Dd
                                : emb_s + (long)qs_skills[qid * 4 + (m - 1)] * Dd;
    float p = src[lane] * kw[lane] + src[lane + 64] * kw[lane + 64];
    for (int off = 32; off > 0; off >>= 1) p += __shfl_xor(p, off);
    a[m] = p + scal[1];
  }
  float mx = a[0];
  for (int m = 1; m < 5; ++m) mx = fmaxf(mx, a[m]);
  float z = 0, ex[5];
  for (int m = 0; m < 5; ++m) { ex[m] = __expf(a[m] - mx); z += ex[m]; }
  if (lane < 5) pm[(long)qid * 5 + lane] = ex[lane] / z;
}

// pointwise LSTM cell (bf16 gates in) + fused a_state = h.qw + scal[0] (f32)
__global__ __launch_bounds__(128) void lstm_point(
    const u16* __restrict__ gI, const u16* __restrict__ gG, const u16* __restrict__ gO,
    const float* __restrict__ qw, const float* __restrict__ scal,
    u16* __restrict__ states, float* __restrict__ a_state)
{
  __shared__ float red[128];
  int rr = blockIdx.x, e = threadIdx.x;
  long idx = (long)rr * Dd + e;
  float c = sigf(bf2f(gI[idx])) * tanhf(bf2f(gG[idx]));
  float h = sigf(bf2f(gO[idx])) * tanhf(c);
  states[idx] = f2bf(h);
  red[e] = h * qw[e];
  __syncthreads();
  for (int s = 64; s > 0; s >>= 1) { if (e < s) red[e] += red[e + s]; __syncthreads(); }
  if (e == 0) a_state[rr] = red[0] + scal[0];
}

// ---------------------------------------------------------------------------
// g_mfma: G[b][col][n] = sigmoid( states[b,n] . qs_vec[b,col] ), col = t*5+m.
// a-side = states (bf16), b-side = gathered emb rows (bf16). G bf16.
// ---------------------------------------------------------------------------
__global__ __launch_bounds__(256) void g_mfma(
    const u16* __restrict__ states, const int* __restrict__ question,
    const int* __restrict__ qs_skills,
    const u16* __restrict__ embq_bf, const u16* __restrict__ embs_bf,
    u16* __restrict__ G)
{
  const int n0 = blockIdx.x * 32;
  const int c0 = blockIdx.y * 128;
  const int b  = blockIdx.z;
  int c_hi = c0 + 127; if (c_hi > 994) c_hi = 994;
  if (n0 > c_hi / 5) return;  // tile entirely n > t: never read

  __shared__ __align__(16) u16 Ql[128 * 136];
  __shared__ __align__(16) u16 Sl[32 * 136];
  const int tid = threadIdx.x;

  { // states tile
    int r = tid & 31, k0 = (tid >> 5) * 16;
    int n = n0 + r; if (n > 198) n = 198;
    const u16* sp = states + ((long)b * Td + n) * 128 + k0;
    *(uint4*)&Sl[r * 136 + k0]     = *(const uint4*)sp;
    *(uint4*)&Sl[r * 136 + k0 + 8] = *(const uint4*)(sp + 8);
  }
  { // qs tile: 2 threads per column, 64 u16 each
    int j = tid >> 1, k0 = (tid & 1) * 64;
    int col = c0 + j;
    uint4* dst = (uint4*)&Ql[j * 136 + k0];
    if (col < 995) {
      int t = col / 5, m = col - t * 5;
      int qn = question[b * Sd + t + 1];
      const u16* src = (m == 0) ? embq_bf + (long)qn * 128
                                : embs_bf + (long)qs_skills[qn * 4 + (m - 1)] * 128;
      src += k0;
#pragma unroll
      for (int q = 0; q < 8; ++q) dst[q] = ((const uint4*)src)[q];
    } else {
      uint4 z = make_uint4(0, 0, 0, 0);
#pragma unroll
      for (int q = 0; q < 8; ++q) dst[q] = z;
    }
  }
  __syncthreads();

  const int lane = tid & 63, wv = tid >> 6;
  const int l15 = lane & 15, quad = lane >> 4;
  const int cw = wv * 32;
  f32x4 acc[2][2];
#pragma unroll
  for (int a = 0; a < 2; ++a)
#pragma unroll
    for (int bb = 0; bb < 2; ++bb) acc[a][bb] = (f32x4){0.f, 0.f, 0.f, 0.f};

#pragma unroll
  for (int kc = 0; kc < 4; ++kc) {
    const int ko = kc * 32 + quad * 8;
    bf16x8 af[2], bfv[2];
    af[0]  = *(const bf16x8*)&Sl[l15 * 136 + ko];
    af[1]  = *(const bf16x8*)&Sl[(16 + l15) * 136 + ko];
    bfv[0] = *(const bf16x8*)&Ql[(cw + l15) * 136 + ko];
    bfv[1] = *(const bf16x8*)&Ql[(cw + 16 + l15) * 136 + ko];
#pragma unroll
    for (int mt = 0; mt < 2; ++mt)
#pragma unroll
      for (int nt = 0; nt < 2; ++nt)
        acc[mt][nt] = __builtin_amdgcn_mfma_f32_16x16x32_bf16(af[mt], bfv[nt], acc[mt][nt], 0, 0, 0);
  }

  // store: 4 regs = 4 consecutive n -> one 8B store
#pragma unroll
  for (int nt = 0; nt < 2; ++nt) {
    int col = c0 + cw + nt * 16 + l15;
    if (col >= 995) continue;
#pragma unroll
    for (int mt = 0; mt < 2; ++mt) {
      int nb = n0 + mt * 16 + quad * 4;
      if (nb > 196) continue;
      u32 lo = (u32)f2bf(sigf(acc[mt][nt][0])) | ((u32)f2bf(sigf(acc[mt][nt][1])) << 16);
      u32 hi = (u32)f2bf(sigf(acc[mt][nt][2])) | ((u32)f2bf(sigf(acc[mt][nt][3])) << 16);
      *(uint2*)&G[((long)b * 1000 + col) * 200 + nb] = make_uint2(lo, hi);
    }
  }
}

// pred[b,t] = sum_{n<=t} pn(n) * sum_m pm(m) * G[b][t*5+m][n] ; out col 0 = 0
__global__ __launch_bounds__(256) void pred_kernel(
    const u16* __restrict__ G, const float* __restrict__ a_state,
    const float* __restrict__ pm, const int* __restrict__ question,
    float* __restrict__ out)
{
  __shared__ float red[256];
  int bt = blockIdx.x;
  int b = bt / Td, t = bt - b * Td;
  int tid = threadIdx.x;

  float v = (tid <= t) ? a_state[b * Td + tid] : -1e30f;
  red[tid] = v; __syncthreads();
  for (int s = 128; s > 0; s >>= 1) { if (tid < s) red[tid] = fmaxf(red[tid], red[tid + s]); __syncthreads(); }
  float amax = red[0]; __syncthreads();

  float ev = (tid <= t) ? __expf(v - amax) : 0.f;
  red[tid] = ev; __syncthreads();
  for (int s = 128; s > 0; s >>= 1) { if (tid < s) red[tid] += red[tid + s]; __syncthreads(); }
  float Z = red[0]; __syncthreads();

  int qn = question[b * Sd + t + 1];
  float p0 = pm[(long)qn * 5 + 0], p1 = pm[(long)qn * 5 + 1], p2 = pm[(long)qn * 5 + 2];
  float p3 = pm[(long)qn * 5 + 3], p4 = pm[(long)qn * 5 + 4];

  float acc = 0.f;
  if (tid <= t) {
    long base = ((long)b * 1000 + (long)t * 5) * 200 + tid;
    float s = p0 * bf2f(G[base])       + p1 * bf2f(G[base + 200]) +
              p2 * bf2f(G[base + 400]) + p3 * bf2f(G[base + 600]) +
              p4 * bf2f(G[base + 800]);
    acc = ev * s;
  }
  red[tid] = acc; __syncthreads();
  for (int s = 128; s > 0; s >>= 1) { if (tid < s) red[tid] += red[tid + s]; __syncthreads(); }
  if (tid == 0) {
    out[b * Sd + t + 1] = red[0] / Z;
    if (t == 0) out[b * Sd] = 0.f;
  }
}

// ---------------------------------------------------------------------------
extern "C" void kernel_launch(void* const* d_in, const int* in_sizes, int n_in,
                              void* d_out, int out_size, void* d_ws, size_t ws_size,
                              hipStream_t stream)
{
  const int*   question = (const int*)d_in[0];
  const int*   response = (const int*)d_in[1];
  const int*   q_nb     = (const int*)d_in[3];
  const int*   s_nb     = (const int*)d_in[4];
  const int*   qs_sk    = (const int*)d_in[5];
  const float* emb_q    = (const float*)d_in[6];
  const float* emb_s    = (const float*)d_in[7];
  const float* emb_r    = (const float*)d_in[8];
  const float* W_ih     = (const float*)d_in[9];
  const float* b_ih     = (const float*)d_in[10];
  const float* b_hh     = (const float*)d_in[11];
  const float* ft_W     = (const float*)d_in[12];
  const float* ft_b     = (const float*)d_in[13];
  const float* agg_W    = (const float*)d_in[14];
  const float* agg_b    = (const float*)d_in[15];
  const float* last_W   = (const float*)d_in[16];
  const float* last_b   = (const float*)d_in[17];
  const float* q_W      = (const float*)d_in[18];
  const float* q_b      = (const float*)d_in[19];
  const float* k_W      = (const float*)d_in[20];
  const float* k_b      = (const float*)d_in[21];
  const float* w_W      = (const float*)d_in[22];

  const long NT = 1280000;  // NQ*128 u16
  const long ST = 64000;
  const long RT = (long)Bd * Td * Dd;  // 815,104
  u16* wsu   = (u16*)d_ws;
  u16* tabA  = wsu;             // table slots (dead before G written)
  u16* tabB  = tabA + NT;
  u16* tabC  = tabB + NT;
  u16* tabs1 = tabC + NT;
  u16* tabs2 = tabs1 + ST;
  u16* gI    = tabs2 + ST;
  u16* gG    = gI + RT;
  u16* gO    = gG + RT;         // ends 6,413,312
  u16* G     = wsu;             // 6,400,000 u16, overlays tabA..gO (all dead)
  u16* states  = gO + RT;       // live past G
  u16* embq_bf = states + RT;
  u16* embs_bf = embq_bf + NT;
  u16* wts     = embs_bf + ST;  // aggt0|aggt1|aggt2|lastt|ftt
  u16* wiht    = wts + 5 * 16384;
  float* fp      = (float*)(wiht + 65536);
  float* a_state = fp;              // 6400
  float* qw      = a_state + 6400;  // 128
  float* kw      = qw + 128;        // 128
  float* scal    = kw + 128;        // 16
  float* er_part = scal + 16;       // 1024
  float* pm      = er_part + 1024;  // 50,000
  int* qid_map   = (int*)(pm + 50000);
  int* resp_map  = qid_map + Bd * Td;

  prep_w<<<512, 256, 0, stream>>>(emb_q, emb_s, agg_W, last_W, ft_W, W_ih,
                                  embq_bf, embs_bf, wts, wiht);
  prep_small<<<1, 512, 0, stream>>>(q_W, q_b, k_W, k_b, w_W, W_ih, b_ih, b_hh, emb_r,
                                    qw, kw, scal, er_part);
  prep_maps<<<(Bd * Td + 255) / 256, 256, 0, stream>>>(question, response, qid_map, resp_map);
  pm_kernel<<<NQd / 4, 256, 0, stream>>>(emb_q, emb_s, qs_sk, kw, scal, pm);

  // hop 0
  stage_mfma<<<313, 256, 0, stream>>>(embq_bf, embs_bf, q_nb, 4, nullptr,
      wts + 2 * 16384, 0, agg_b + 256, nullptr, nullptr, 0, tabA, NQd, 0, 0);  // f2
  stage_mfma<<<16, 256, 0, stream>>>(embs_bf, embq_bf, s_nb, 10, nullptr,
      wts + 16384, 0, agg_b + 128, nullptr, nullptr, 0, tabs1, NSd, 0, 0);     // f1
  stage_mfma<<<313, 256, 0, stream>>>(embq_bf, embs_bf, q_nb, 4, nullptr,
      wts, 0, agg_b, nullptr, nullptr, 0, tabB, NQd, 0, 0);                    // f0
  // hop 1
  stage_mfma<<<16, 256, 0, stream>>>(tabs1, tabA, s_nb, 10, nullptr,
      wts + 16384, 0, agg_b + 128, nullptr, nullptr, 0, tabs2, NSd, 0, 0);     // g1
  stage_mfma<<<313, 256, 0, stream>>>(tabB, tabs1, q_nb, 4, nullptr,
      wts, 0, agg_b, nullptr, nullptr, 0, tabC, NQd, 0, 0);                    // g0
  // hop 2
  stage_mfma<<<313, 256, 0, stream>>>(tabC, tabs2, q_nb, 4, nullptr,
      wts, 0, agg_b, nullptr, nullptr, 0, tabA, NQd, 0, 0);                    // h0
  // agg = tanh(h0 @ last_W + last_b)
  stage_mfma<<<313, 256, 0, stream>>>(tabA, nullptr, nullptr, 0, nullptr,
      wts + 3 * 16384, 0, last_b, nullptr, nullptr, 0, tabB, NQd, 0, 0);       // agg
  // qt = relu(agg @ ft_W + ft_b)
  stage_mfma<<<313, 256, 0, stream>>>(tabB, nullptr, nullptr, 0, nullptr,
      wts + 4 * 16384, 0, ft_b, nullptr, nullptr, 0, tabC, NQd, 1, 0);         // qt
  // gates i/g/o in one launch (blockIdx.y selects gate; outs contiguous)
  stage_mfma<<<dim3(199, 3), 256, 0, stream>>>(tabC, nullptr, nullptr, 0, qid_map,
      wiht, 0, nullptr, er_part, resp_map, 0, gI, Bd * Td, 2, 1);

  lstm_point<<<Bd * Td, 128, 0, stream>>>(gI, gG, gO, qw, scal, states, a_state);

  g_mfma<<<dim3(7, 8, Bd), 256, 0, stream>>>(states, question, qs_sk, embq_bf, embs_bf, G);

  pred_kernel<<<Bd * Td, 256, 0, stream>>>(G, a_state, pm, question, (float*)d_out);
}